// Round 7
// baseline (382.011 us; speedup 1.0000x reference)
//
#include <hip/hip_runtime.h>
#include <hip/hip_bf16.h>

// BinaryMoSLinear: B=4, S=2048 -> N=8192 rows; H=O=4096; E=4.
#define H_DIM 4096
#define O_DIM 4096
#define N_ROWS 8192

typedef __bf16 bf16x8 __attribute__((ext_vector_type(8)));
typedef float  f32x4  __attribute__((ext_vector_type(4)));

__device__ __forceinline__ unsigned short f32_bf16_rne(float f) {
    unsigned int u = __builtin_bit_cast(unsigned int, f);
    u += 0x7FFFu + ((u >> 16) & 1u);
    return (unsigned short)(u >> 16);
}

__device__ __forceinline__ void gload_lds16(const unsigned short* g, unsigned short* l) {
    __builtin_amdgcn_global_load_lds((const __attribute__((address_space(1))) void*)g,
                                     (__attribute__((address_space(3))) void*)l,
                                     16, 0, 0);
}
__device__ __forceinline__ void gload_lds16b(const unsigned char* g, char* l) {
    __builtin_amdgcn_global_load_lds((const __attribute__((address_space(1))) void*)g,
                                     (__attribute__((address_space(3))) void*)l,
                                     16, 0, 0);
}

// Expand 8 sign-bytes (0x3F=+1, 0xBF=-1, 0x00=0 — the bf16 HIGH byte) into
// bf16x8: half = (b<<8) | ((b&1)<<7). 0x3F->0x3F80, 0xBF->0xBF80, 0->0x0000.
// Per dword: s=(v&0x01010101)<<7 (lo bytes), then v_perm interleaves
// [s.b0,v.b0,s.b1,v.b1] / [s.b2,v.b2,s.b3,v.b3].  8 VALU per frag.
__device__ __forceinline__ bf16x8 b8_to_bf16x8(uint2 raw) {
    unsigned r0 = raw.x, r1 = raw.y;
    unsigned s0 = (r0 & 0x01010101u) << 7;
    unsigned s1 = (r1 & 0x01010101u) << 7;
    uint4 o;
    o.x = __builtin_amdgcn_perm(r0, s0, 0x05010400u);
    o.y = __builtin_amdgcn_perm(r0, s0, 0x07030602u);
    o.z = __builtin_amdgcn_perm(r1, s1, 0x05010400u);
    o.w = __builtin_amdgcn_perm(r1, s1, 0x07030602u);
    return __builtin_bit_cast(bf16x8, o);
}

// ---------------------------------------------------------------------------
// Kernel 1: bw = sign(weight) as 1 BYTE: 0x3F (+1), 0xBF (-1), 0x00 (0).
// ---------------------------------------------------------------------------
__global__ void __launch_bounds__(256) sign_kernel(const float* __restrict__ w,
                                                   unsigned char* __restrict__ bw) {
    size_t i = ((size_t)blockIdx.x * 256 + threadIdx.x) * 8;
    float4 a = *reinterpret_cast<const float4*>(w + i);
    float4 b = *reinterpret_cast<const float4*>(w + i + 4);
    const float* v[2] = {&a.x, &b.x};
    unsigned int p[2];
#pragma unroll
    for (int d = 0; d < 2; ++d) {
        unsigned int r = 0;
#pragma unroll
        for (int j = 0; j < 4; ++j) {
            float f = v[d][j];
            unsigned int byte = f > 0.f ? 0x3Fu : (f < 0.f ? 0xBFu : 0u);
            r |= byte << (8 * j);
        }
        p[d] = r;
    }
    *reinterpret_cast<uint2*>(bw + i) = make_uint2(p[0], p[1]);
}

// ---------------------------------------------------------------------------
// Kernel 2: router softmax -> rw[n][4]; xs = bf16(x * (rw @ in_channel_scale)).
// ---------------------------------------------------------------------------
__global__ void __launch_bounds__(256) route_scale_kernel(
    const float* __restrict__ x, const float* __restrict__ gate_w,
    const float* __restrict__ ics, float* __restrict__ rw_out,
    unsigned short* __restrict__ xs_out)
{
    __shared__ float red[4][4];
    const int n = blockIdx.x;
    const int t = threadIdx.x;
    const float* xr = x + (size_t)n * H_DIM;

    float4 xv[4];
    float lg[4] = {0.f, 0.f, 0.f, 0.f};
#pragma unroll
    for (int c = 0; c < 4; ++c) {
        const int idx = c * 1024 + t * 4;
        xv[c] = *reinterpret_cast<const float4*>(xr + idx);
#pragma unroll
        for (int e = 0; e < 4; ++e) {
            float4 g = *reinterpret_cast<const float4*>(gate_w + e * H_DIM + idx);
            lg[e] += xv[c].x * g.x + xv[c].y * g.y + xv[c].z * g.z + xv[c].w * g.w;
        }
    }
#pragma unroll
    for (int e = 0; e < 4; ++e) {
#pragma unroll
        for (int off = 1; off < 64; off <<= 1)
            lg[e] += __shfl_xor(lg[e], off, 64);
    }
    if ((t & 63) == 0) {
        const int w = t >> 6;
        red[w][0] = lg[0]; red[w][1] = lg[1]; red[w][2] = lg[2]; red[w][3] = lg[3];
    }
    __syncthreads();
    const float l0 = red[0][0] + red[1][0] + red[2][0] + red[3][0];
    const float l1 = red[0][1] + red[1][1] + red[2][1] + red[3][1];
    const float l2 = red[0][2] + red[1][2] + red[2][2] + red[3][2];
    const float l3 = red[0][3] + red[1][3] + red[2][3] + red[3][3];
    const float m  = fmaxf(fmaxf(l0, l1), fmaxf(l2, l3));
    const float p0 = expf(l0 - m), p1 = expf(l1 - m), p2 = expf(l2 - m), p3 = expf(l3 - m);
    const float inv = 1.f / (p0 + p1 + p2 + p3);
    const float w0 = p0 * inv, w1 = p1 * inv, w2 = p2 * inv, w3 = p3 * inv;
    if (t == 0) {
        float4 wv = make_float4(w0, w1, w2, w3);
        *reinterpret_cast<float4*>(rw_out + (size_t)n * 4) = wv;
    }
#pragma unroll
    for (int c = 0; c < 4; ++c) {
        const int idx = c * 1024 + t * 4;
        float4 i0 = *reinterpret_cast<const float4*>(ics + 0 * H_DIM + idx);
        float4 i1 = *reinterpret_cast<const float4*>(ics + 1 * H_DIM + idx);
        float4 i2 = *reinterpret_cast<const float4*>(ics + 2 * H_DIM + idx);
        float4 i3 = *reinterpret_cast<const float4*>(ics + 3 * H_DIM + idx);
        const float sx = w0 * i0.x + w1 * i1.x + w2 * i2.x + w3 * i3.x;
        const float sy = w0 * i0.y + w1 * i1.y + w2 * i2.y + w3 * i3.y;
        const float sz = w0 * i0.z + w1 * i1.z + w2 * i2.z + w3 * i3.z;
        const float sw = w0 * i0.w + w1 * i1.w + w2 * i2.w + w3 * i3.w;
        ushort4 o;
        o.x = f32_bf16_rne(xv[c].x * sx);
        o.y = f32_bf16_rne(xv[c].y * sy);
        o.z = f32_bf16_rne(xv[c].z * sz);
        o.w = f32_bf16_rne(xv[c].w * sw);
        *reinterpret_cast<ushort4*>(xs_out + (size_t)n * H_DIM + idx) = o;
    }
}

// ---------------------------------------------------------------------------
// Kernel 3: C = (xs @ bw^T) * (rw @ ocs) + bias  — R3 structure (best: 243µs,
// 0 conflicts, 16x16x32 MFMA) + B staged as SIGN BYTES (halves B LDS traffic:
// block-window LDS pipe 128KB -> 104KB; the co-bottleneck with MFMA).
//
// LDS map: A slot s @ s*16384 (256 rows x 64B bf16, R3 chunk-XOR swizzle);
//          B slot s @ 65536 + s*8192 (256 cols x 32B of sign bytes). 96 KiB.
// B byte layout: byte (col,k) at col*32 + (k ^ ((col>>1)&2))*8 + (k&7)
//   (k-group kg = k/8; 16B-granular source pre-swizzle: staging thread t ->
//   col t>>1, phys 16B chunk m=t&1 sources global offset 16*(m^((col>>2)&1));
//   involution verified both sides). Residual aliasing: cols 8 apart, 2-way —
//   same class as R3's A rows-8-apart (measured free, 0 conflicts).
// B frag read: ds_read_b64 (8 bytes) -> expand to bf16x8 post-MFMA (8 VALU,
//   lgkm already drained there; feeds NEXT window via ping-pong like A).
// Ledger (batch now 3 calls: A j0, A j1, B):
//   prologue stages T0,T1,T2 (9 calls); vmcnt(3) retires T0,T1; barrier.
//   window W: stage T(W+3); vmcnt(3) retires T(W+2); wall; reads T(W+1)
//     (8 A b128 + 4 B b64); wall; 32 MFMA on cur sets + B expand; wall;
//     barrier.  Tail: W=124 stages T127; 125 vmcnt(0); 126/127 no gate.
// ---------------------------------------------------------------------------

#define GATE3 asm volatile("s_waitcnt vmcnt(3)" ::: "memory")
#define GATE0 asm volatile("s_waitcnt vmcnt(0)" ::: "memory")
#define NOGATE

#define WINDOW(W, CA_, CB_, NA_, NB_, DO_STAGE, GATE_STMT, DO_READS, DO_BAR)    \
  {                                                                             \
    const int w_ = (W);                                                         \
    if (DO_STAGE) {                                                             \
      const int ks_ = w_ + 3;                                                   \
      char* sA_ = lds + (ks_ & 3) * 16384;                                      \
      char* sB_ = lds + 65536 + (ks_ & 3) * 8192;                               \
      _Pragma("unroll")                                                         \
      for (int j = 0; j < 2; ++j)                                               \
        gload_lds16(gA + ((size_t)j * 128) * H_DIM + ks_ * 32,                  \
                    (unsigned short*)(sA_ + j * 8192 + wv * 1024));             \
      gload_lds16b(gBb + ks_ * 32, sB_ + wv * 1024);                            \
    }                                                                           \
    GATE_STMT;                                                                  \
    __builtin_amdgcn_sched_barrier(0);                                          \
    uint2 braw0, braw1, braw2, braw3;                                           \
    if (DO_READS) {                                                             \
      const int sbA = ((w_ + 1) & 3) * 16384;                                   \
      const int sbB = 65536 + ((w_ + 1) & 3) * 8192;                            \
      _Pragma("unroll")                                                         \
      for (int fr = 0; fr < 8; ++fr)                                            \
        NA_[fr] = *reinterpret_cast<const bf16x8*>(lds + sbA + aOff[fr]);       \
      braw0 = *reinterpret_cast<const uint2*>(lds + sbB + bOffB[0]);            \
      braw1 = *reinterpret_cast<const uint2*>(lds + sbB + bOffB[1]);            \
      braw2 = *reinterpret_cast<const uint2*>(lds + sbB + bOffB[2]);            \
      braw3 = *reinterpret_cast<const uint2*>(lds + sbB + bOffB[3]);            \
    }                                                                           \
    __builtin_amdgcn_sched_barrier(0);                                          \
    __builtin_amdgcn_s_setprio(1);                                              \
    _Pragma("unroll")                                                           \
    for (int fr = 0; fr < 8; ++fr)                                              \
      _Pragma("unroll")                                                         \
      for (int ni = 0; ni < 4; ++ni)                                            \
        acc[fr][ni] = __builtin_amdgcn_mfma_f32_16x16x32_bf16(CA_[fr], CB_[ni], \
                                                              acc[fr][ni], 0, 0, 0); \
    __builtin_amdgcn_s_setprio(0);                                              \
    if (DO_READS) {                                                             \
      NB_[0] = b8_to_bf16x8(braw0);                                             \
      NB_[1] = b8_to_bf16x8(braw1);                                             \
      NB_[2] = b8_to_bf16x8(braw2);                                             \
      NB_[3] = b8_to_bf16x8(braw3);                                             \
    }                                                                           \
    __builtin_amdgcn_sched_barrier(0);                                          \
    if (DO_BAR) __builtin_amdgcn_s_barrier();                                   \
  }

__global__ void __launch_bounds__(512, 2) gemm_bin_kernel(
    const unsigned short* __restrict__ xs,   // [N_ROWS][H] bf16
    const unsigned char*  __restrict__ bwb,  // [O][H] sign bytes
    const float* __restrict__ rw,            // [N_ROWS][4]
    const float* __restrict__ ocs,           // [4][O]
    const float* __restrict__ bias,          // [O]
    float* __restrict__ out)                 // [N_ROWS][O]
{
    __shared__ __align__(16) char lds[98304];   // 4*16K A + 4*8K B

    const int t  = threadIdx.x;
    const int wv = t >> 6;
    const int ln = t & 63;
    const int wr = wv >> 2;          // 0..1 -> 128-row half
    const int wc = wv & 3;           // 0..3 -> 64-col quarter

    // T1: bijective XCD swizzle (512 blocks, 512%8==0)
    const int bid = blockIdx.x;
    const int swz = (bid & 7) * 64 + (bid >> 3);
    const int rowBase = (swz >> 4) * 256;    // 32 M-tiles
    const int colBase = (swz & 15) * 256;    // 16 N-tiles

    // A staging map (R3): row r = t>>2, physical chunk t&3 holds logical
    // chunk (t&3)^((t>>3)&3)
    const int s_r  = t >> 2;
    const int s_cl = (t & 3) ^ ((t >> 3) & 3);
    const unsigned short* gA = xs + (size_t)(rowBase + s_r) * H_DIM + s_cl * 8;

    // B staging map: col = t>>1, phys 16B chunk m = t&1 sources global
    // offset 16*(m ^ ((col>>2)&1)) within the 32-byte window region.
    const int s_colB = t >> 1;
    const int s_mB   = (t & 1) ^ ((s_colB >> 2) & 1);
    const unsigned char* gBb = bwb + (size_t)(colBase + s_colB) * H_DIM + s_mB * 16;

    // read-side offsets (loop-invariant)
    int aOff[8], bOffB[4];
#pragma unroll
    for (int fr = 0; fr < 8; ++fr) {
        const int row = wr * 128 + fr * 16 + (ln & 15);
        aOff[fr] = row * 64 + (((ln >> 4) ^ ((row >> 1) & 3)) << 4);
    }
#pragma unroll
    for (int ni = 0; ni < 4; ++ni) {
        const int col = wc * 64 + ni * 16 + (ln & 15);
        const int kg  = ln >> 4;
        bOffB[ni] = col * 32 + ((kg ^ ((col >> 1) & 2)) << 3);
    }

    f32x4 acc[8][4];
#pragma unroll
    for (int i = 0; i < 8; ++i)
#pragma unroll
        for (int j = 0; j < 4; ++j) acc[i][j] = (f32x4){0.f, 0.f, 0.f, 0.f};

    // ---- prologue: stage tiles 0,1,2 (slots 0,1,2) ----
#pragma unroll
    for (int kt = 0; kt < 3; ++kt) {
        char* sA = lds + kt * 16384;
        char* sB = lds + 65536 + kt * 8192;
#pragma unroll
        for (int j = 0; j < 2; ++j)
            gload_lds16(gA + ((size_t)j * 128) * H_DIM + kt * 32,
                        (unsigned short*)(sA + j * 8192 + wv * 1024));
        gload_lds16b(gBb + kt * 32, sB + wv * 1024);
    }
    GATE3;                               // retires T0,T1 (leaves T2's 3 flying)
    __builtin_amdgcn_s_barrier();        // -> T0,T1 certified block-wide

    // preload current register sets from tile 0 (slot 0)
    bf16x8 avA[8], bvA[4], avB[8], bvB[4];
#pragma unroll
    for (int fr = 0; fr < 8; ++fr)
        avA[fr] = *reinterpret_cast<const bf16x8*>(lds + aOff[fr]);
#pragma unroll
    for (int ni = 0; ni < 4; ++ni) {
        uint2 r = *reinterpret_cast<const uint2*>(lds + 65536 + bOffB[ni]);
        bvA[ni] = b8_to_bf16x8(r);
    }

    // ---- main loop: windows 0..123 (steady), 124..127 peeled ----
    for (int w = 0; w < 124; w += 2) {
        WINDOW(w,     avA, bvA, avB, bvB, 1, GATE3, 1, 1);
        WINDOW(w + 1, avB, bvB, avA, bvA, 1, GATE3, 1, 1);
    }
    WINDOW(124, avA, bvA, avB, bvB, 1, GATE3,  1, 1);   // stages T127 (last)
    WINDOW(125, avB, bvB, avA, bvA, 0, GATE0,  1, 1);   // certify T127
    WINDOW(126, avA, bvA, avB, bvB, 0, NOGATE, 1, 1);
    WINDOW(127, avB, bvB, avA, bvA, 0, NOGATE, 0, 0);

    // ---- epilogue: y = acc * (rw . ocs[:,col]) + bias  (R3 verbatim) ----
    float oce[4][4], bve[4];
    int cole[4];
#pragma unroll
    for (int ni = 0; ni < 4; ++ni) {
        const int col = colBase + wc * 64 + ni * 16 + (ln & 15);
        cole[ni] = col;
        oce[ni][0] = ocs[0 * O_DIM + col];
        oce[ni][1] = ocs[1 * O_DIM + col];
        oce[ni][2] = ocs[2 * O_DIM + col];
        oce[ni][3] = ocs[3 * O_DIM + col];
        bve[ni] = bias[col];
    }
#pragma unroll
    for (int fr = 0; fr < 8; ++fr) {
        float4 rwv[4];
        int rowe[4];
#pragma unroll
        for (int j = 0; j < 4; ++j) {
            const int row = rowBase + wr * 128 + fr * 16 + (ln >> 4) * 4 + j;
            rowe[j] = row;
            rwv[j] = *reinterpret_cast<const float4*>(rw + (size_t)row * 4);
        }
#pragma unroll
        for (int ni = 0; ni < 4; ++ni) {
#pragma unroll
            for (int j = 0; j < 4; ++j) {
                const float os = rwv[j].x * oce[ni][0] + rwv[j].y * oce[ni][1] +
                                 rwv[j].z * oce[ni][2] + rwv[j].w * oce[ni][3];
                out[(size_t)rowe[j] * O_DIM + cole[ni]] = acc[fr][ni][j] * os + bve[ni];
            }
        }
    }
}

// ---------------------------------------------------------------------------
extern "C" void kernel_launch(void* const* d_in, const int* in_sizes, int n_in,
                              void* d_out, int out_size, void* d_ws, size_t ws_size,
                              hipStream_t stream) {
    const float* x      = (const float*)d_in[0];
    const float* weight = (const float*)d_in[1];
    const float* bias   = (const float*)d_in[2];
    const float* gate_w = (const float*)d_in[3];
    const float* ics    = (const float*)d_in[4];
    const float* ocs    = (const float*)d_in[5];
    float* out = (float*)d_out;

    unsigned short* xs = (unsigned short*)d_ws;                      // [N][H] bf16
    unsigned char*  bwb = (unsigned char*)(xs + (size_t)N_ROWS * H_DIM); // [O][H] bytes
    float* rw = (float*)(bwb + (size_t)O_DIM * H_DIM);               // [N][4]

    sign_kernel<<<(O_DIM * H_DIM) / (256 * 8), 256, 0, stream>>>(weight, bwb);
    route_scale_kernel<<<N_ROWS, 256, 0, stream>>>(x, gate_w, ics, rw, xs);
    gemm_bin_kernel<<<(N_ROWS / 256) * (O_DIM / 256), 512, 0, stream>>>(xs, bwb, rw, ocs, bias, out);
}

// Round 8
// 317.874 us; speedup vs baseline: 1.2018x; 1.2018x over previous
//
#include <hip/hip_runtime.h>
#include <hip/hip_bf16.h>

// BinaryMoSLinear: B=4, S=2048 -> N=8192 rows; H=O=4096; E=4.
#define H_DIM 4096
#define O_DIM 4096
#define N_ROWS 8192

typedef __bf16 bf16x8 __attribute__((ext_vector_type(8)));
typedef float  f32x4  __attribute__((ext_vector_type(4)));

__device__ __forceinline__ unsigned short f32_bf16_rne(float f) {
    unsigned int u = __builtin_bit_cast(unsigned int, f);
    u += 0x7FFFu + ((u >> 16) & 1u);
    return (unsigned short)(u >> 16);
}

__device__ __forceinline__ void gload_lds16(const unsigned short* g, unsigned short* l) {
    __builtin_amdgcn_global_load_lds((const __attribute__((address_space(1))) void*)g,
                                     (__attribute__((address_space(3))) void*)l,
                                     16, 0, 0);
}

// ---------------------------------------------------------------------------
// Kernel 1: bw = sign(weight) as bf16 (+1.0 / -1.0 / 0.0).
// ---------------------------------------------------------------------------
__global__ void __launch_bounds__(256) sign_kernel(const float* __restrict__ w,
                                                   unsigned short* __restrict__ bw) {
    size_t i = ((size_t)blockIdx.x * 256 + threadIdx.x) * 4;
    float4 v = *reinterpret_cast<const float4*>(w + i);
    ushort4 o;
    o.x = v.x > 0.f ? 0x3F80 : (v.x < 0.f ? 0xBF80 : 0);
    o.y = v.y > 0.f ? 0x3F80 : (v.y < 0.f ? 0xBF80 : 0);
    o.z = v.z > 0.f ? 0x3F80 : (v.z < 0.f ? 0xBF80 : 0);
    o.w = v.w > 0.f ? 0x3F80 : (v.w < 0.f ? 0xBF80 : 0);
    *reinterpret_cast<ushort4*>(bw + i) = o;
}

// ---------------------------------------------------------------------------
// Kernel 2: router softmax -> rw[n][4]; xs = bf16(x * (rw @ in_channel_scale)).
// ---------------------------------------------------------------------------
__global__ void __launch_bounds__(256) route_scale_kernel(
    const float* __restrict__ x, const float* __restrict__ gate_w,
    const float* __restrict__ ics, float* __restrict__ rw_out,
    unsigned short* __restrict__ xs_out)
{
    __shared__ float red[4][4];
    const int n = blockIdx.x;
    const int t = threadIdx.x;
    const float* xr = x + (size_t)n * H_DIM;

    float4 xv[4];
    float lg[4] = {0.f, 0.f, 0.f, 0.f};
#pragma unroll
    for (int c = 0; c < 4; ++c) {
        const int idx = c * 1024 + t * 4;
        xv[c] = *reinterpret_cast<const float4*>(xr + idx);
#pragma unroll
        for (int e = 0; e < 4; ++e) {
            float4 g = *reinterpret_cast<const float4*>(gate_w + e * H_DIM + idx);
            lg[e] += xv[c].x * g.x + xv[c].y * g.y + xv[c].z * g.z + xv[c].w * g.w;
        }
    }
#pragma unroll
    for (int e = 0; e < 4; ++e) {
#pragma unroll
        for (int off = 1; off < 64; off <<= 1)
            lg[e] += __shfl_xor(lg[e], off, 64);
    }
    if ((t & 63) == 0) {
        const int w = t >> 6;
        red[w][0] = lg[0]; red[w][1] = lg[1]; red[w][2] = lg[2]; red[w][3] = lg[3];
    }
    __syncthreads();
    const float l0 = red[0][0] + red[1][0] + red[2][0] + red[3][0];
    const float l1 = red[0][1] + red[1][1] + red[2][1] + red[3][1];
    const float l2 = red[0][2] + red[1][2] + red[2][2] + red[3][2];
    const float l3 = red[0][3] + red[1][3] + red[2][3] + red[3][3];
    const float m  = fmaxf(fmaxf(l0, l1), fmaxf(l2, l3));
    const float p0 = expf(l0 - m), p1 = expf(l1 - m), p2 = expf(l2 - m), p3 = expf(l3 - m);
    const float inv = 1.f / (p0 + p1 + p2 + p3);
    const float w0 = p0 * inv, w1 = p1 * inv, w2 = p2 * inv, w3 = p3 * inv;
    if (t == 0) {
        float4 wv = make_float4(w0, w1, w2, w3);
        *reinterpret_cast<float4*>(rw_out + (size_t)n * 4) = wv;
    }
#pragma unroll
    for (int c = 0; c < 4; ++c) {
        const int idx = c * 1024 + t * 4;
        float4 i0 = *reinterpret_cast<const float4*>(ics + 0 * H_DIM + idx);
        float4 i1 = *reinterpret_cast<const float4*>(ics + 1 * H_DIM + idx);
        float4 i2 = *reinterpret_cast<const float4*>(ics + 2 * H_DIM + idx);
        float4 i3 = *reinterpret_cast<const float4*>(ics + 3 * H_DIM + idx);
        const float sx = w0 * i0.x + w1 * i1.x + w2 * i2.x + w3 * i3.x;
        const float sy = w0 * i0.y + w1 * i1.y + w2 * i2.y + w3 * i3.y;
        const float sz = w0 * i0.z + w1 * i1.z + w2 * i2.z + w3 * i3.z;
        const float sw = w0 * i0.w + w1 * i1.w + w2 * i2.w + w3 * i3.w;
        ushort4 o;
        o.x = f32_bf16_rne(xv[c].x * sx);
        o.y = f32_bf16_rne(xv[c].y * sy);
        o.z = f32_bf16_rne(xv[c].z * sz);
        o.w = f32_bf16_rne(xv[c].w * sw);
        *reinterpret_cast<ushort4*>(xs_out + (size_t)n * H_DIM + idx) = o;
    }
}

// ---------------------------------------------------------------------------
// Kernel 3: C = (xs @ bw^T) * (rw @ ocs) + bias  — R3 structure, WALLS REMOVED.
//
// R1-R7 all carried sched_barrier(0) between the ds_read block and the MFMA
// cluster (rule #18 overcaution — that rule is for inline-asm ds_reads; ours
// are compiler-visible loads). m141 evidence: such order-pinning defeats the
// compiler's fine-grained lgkmcnt(N) interleave (880->510 TF there). This
// round: identical R3 ledger/swizzle/structure, zero sched_barrier walls.
// Ordering without walls: gate asm keeps "memory" clobber (fences gload_lds
// and ds_reads); MFMA->operand is register dependency; s_barrier fences the
// window boundary. Ledger (proven): prologue stages T0,T1,T2; vmcnt(4)
// retires T0,T1; barrier. Window W: stage T(W+3); vmcnt(4); 12 ds_reads of
// T(W+1) -> ping-pong set; 32 MFMA on current set; barrier. Tail: W=124
// stages T127; W=125 vmcnt(0); 126/127 no gate.
// Swizzle (0 conflicts): logical (row, 16B-chunk c) at physical chunk
// c ^ ((row>>1)&3); applied on pre-swizzled global source and LDS read.
// LDS: A slot s @ s*16384 (256 rows x 64 B); B slot s @ 65536 + s*16384.
// ---------------------------------------------------------------------------

#define GATE4 asm volatile("s_waitcnt vmcnt(4)" ::: "memory")
#define GATE0 asm volatile("s_waitcnt vmcnt(0)" ::: "memory")
#define NOGATE

#define WINDOW(W, CA_, CB_, NA_, NB_, DO_STAGE, GATE_STMT, DO_READS, DO_BAR)    \
  {                                                                             \
    const int w_ = (W);                                                         \
    if (DO_STAGE) {                                                             \
      const int ks_ = w_ + 3;                                                   \
      char* sA_ = lds + (ks_ & 3) * 16384;                                      \
      char* sB_ = lds + 65536 + (ks_ & 3) * 16384;                              \
      _Pragma("unroll")                                                         \
      for (int j = 0; j < 2; ++j) {                                             \
        gload_lds16(gA + ((size_t)j * 128) * H_DIM + ks_ * 32,                  \
                    (unsigned short*)(sA_ + j * 8192 + wv * 1024));             \
        gload_lds16(gB + ((size_t)j * 128) * H_DIM + ks_ * 32,                  \
                    (unsigned short*)(sB_ + j * 8192 + wv * 1024));             \
      }                                                                         \
    }                                                                           \
    GATE_STMT;                                                                  \
    if (DO_READS) {                                                             \
      const int sb_ = ((w_ + 1) & 3) * 16384;                                   \
      _Pragma("unroll")                                                         \
      for (int fr = 0; fr < 8; ++fr)                                            \
        NA_[fr] = *reinterpret_cast<const bf16x8*>(lds + sb_ + aOff[fr]);       \
      _Pragma("unroll")                                                         \
      for (int ni = 0; ni < 4; ++ni)                                            \
        NB_[ni] = *reinterpret_cast<const bf16x8*>(lds + 65536 + sb_ + bOff[ni]); \
    }                                                                           \
    __builtin_amdgcn_s_setprio(1);                                              \
    _Pragma("unroll")                                                           \
    for (int fr = 0; fr < 8; ++fr)                                              \
      _Pragma("unroll")                                                         \
      for (int ni = 0; ni < 4; ++ni)                                            \
        acc[fr][ni] = __builtin_amdgcn_mfma_f32_16x16x32_bf16(CA_[fr], CB_[ni], \
                                                              acc[fr][ni], 0, 0, 0); \
    __builtin_amdgcn_s_setprio(0);                                              \
    if (DO_BAR) __builtin_amdgcn_s_barrier();                                   \
  }

__global__ void __launch_bounds__(512, 2) gemm_bin_kernel(
    const unsigned short* __restrict__ xs,   // [N_ROWS][H] bf16
    const unsigned short* __restrict__ bw,   // [O][H] bf16 (row = output col)
    const float* __restrict__ rw,            // [N_ROWS][4]
    const float* __restrict__ ocs,           // [4][O]
    const float* __restrict__ bias,          // [O]
    float* __restrict__ out)                 // [N_ROWS][O]
{
    __shared__ __align__(16) char lds[131072];

    const int t  = threadIdx.x;
    const int wv = t >> 6;
    const int ln = t & 63;
    const int wr = wv >> 2;          // 0..1 -> 128-row half
    const int wc = wv & 3;           // 0..3 -> 64-col quarter

    // T1: bijective XCD swizzle (512 blocks, 512%8==0)
    const int bid = blockIdx.x;
    const int swz = (bid & 7) * 64 + (bid >> 3);
    const int rowBase = (swz >> 4) * 256;    // 32 M-tiles
    const int colBase = (swz & 15) * 256;    // 16 N-tiles

    // staging thread map: row r = t>>2, physical chunk t&3 holds logical
    // chunk (t&3)^((t>>3)&3)  [= (t&3)^((row>>1)&3)]
    const int s_r  = t >> 2;
    const int s_cl = (t & 3) ^ ((t >> 3) & 3);
    const unsigned short* gA = xs + (size_t)(rowBase + s_r) * H_DIM + s_cl * 8;
    const unsigned short* gB = bw + (size_t)(colBase + s_r) * H_DIM + s_cl * 8;

    // read-side fragment byte offsets within a slot (loop-invariant)
    int aOff[8], bOff[4];
#pragma unroll
    for (int fr = 0; fr < 8; ++fr) {
        const int row = wr * 128 + fr * 16 + (ln & 15);
        aOff[fr] = row * 64 + (((ln >> 4) ^ ((row >> 1) & 3)) << 4);
    }
#pragma unroll
    for (int ni = 0; ni < 4; ++ni) {
        const int row = wc * 64 + ni * 16 + (ln & 15);
        bOff[ni] = row * 64 + (((ln >> 4) ^ ((row >> 1) & 3)) << 4);
    }

    f32x4 acc[8][4];
#pragma unroll
    for (int i = 0; i < 8; ++i)
#pragma unroll
        for (int j = 0; j < 4; ++j) acc[i][j] = (f32x4){0.f, 0.f, 0.f, 0.f};

    // ---- prologue: stage tiles 0,1,2 (slots 0,1,2) ----
#pragma unroll
    for (int kt = 0; kt < 3; ++kt) {
        char* sA = lds + kt * 16384;
        char* sB = lds + 65536 + kt * 16384;
#pragma unroll
        for (int j = 0; j < 2; ++j) {
            gload_lds16(gA + ((size_t)j * 128) * H_DIM + kt * 32,
                        (unsigned short*)(sA + j * 8192 + wv * 1024));
            gload_lds16(gB + ((size_t)j * 128) * H_DIM + kt * 32,
                        (unsigned short*)(sB + j * 8192 + wv * 1024));
        }
    }
    GATE4;                               // retires T0,T1 (leaves T2 flying)
    __builtin_amdgcn_s_barrier();        // -> T0,T1 certified block-wide

    // preload current register set from tile 0 (slot 0)
    bf16x8 avA[8], bvA[4], avB[8], bvB[4];
#pragma unroll
    for (int fr = 0; fr < 8; ++fr)
        avA[fr] = *reinterpret_cast<const bf16x8*>(lds + aOff[fr]);
#pragma unroll
    for (int ni = 0; ni < 4; ++ni)
        bvA[ni] = *reinterpret_cast<const bf16x8*>(lds + 65536 + bOff[ni]);

    // ---- main loop: windows 0..123 (steady), 124..127 peeled ----
    for (int w = 0; w < 124; w += 2) {
        WINDOW(w,     avA, bvA, avB, bvB, 1, GATE4, 1, 1);
        WINDOW(w + 1, avB, bvB, avA, bvA, 1, GATE4, 1, 1);
    }
    WINDOW(124, avA, bvA, avB, bvB, 1, GATE4,  1, 1);   // stages T127 (last)
    WINDOW(125, avB, bvB, avA, bvA, 0, GATE0,  1, 1);   // certify T127
    WINDOW(126, avA, bvA, avB, bvB, 0, NOGATE, 1, 1);
    WINDOW(127, avB, bvB, avA, bvA, 0, NOGATE, 0, 0);

    // ---- epilogue: y = acc * (rw . ocs[:,col]) + bias ----
    float oce[4][4], bve[4];
    int cole[4];
#pragma unroll
    for (int ni = 0; ni < 4; ++ni) {
        const int col = colBase + wc * 64 + ni * 16 + (ln & 15);
        cole[ni] = col;
        oce[ni][0] = ocs[0 * O_DIM + col];
        oce[ni][1] = ocs[1 * O_DIM + col];
        oce[ni][2] = ocs[2 * O_DIM + col];
        oce[ni][3] = ocs[3 * O_DIM + col];
        bve[ni] = bias[col];
    }
#pragma unroll
    for (int fr = 0; fr < 8; ++fr) {
        float4 rwv[4];
        int rowe[4];
#pragma unroll
        for (int j = 0; j < 4; ++j) {
            const int row = rowBase + wr * 128 + fr * 16 + (ln >> 4) * 4 + j;
            rowe[j] = row;
            rwv[j] = *reinterpret_cast<const float4*>(rw + (size_t)row * 4);
        }
#pragma unroll
        for (int ni = 0; ni < 4; ++ni) {
#pragma unroll
            for (int j = 0; j < 4; ++j) {
                const float os = rwv[j].x * oce[ni][0] + rwv[j].y * oce[ni][1] +
                                 rwv[j].z * oce[ni][2] + rwv[j].w * oce[ni][3];
                out[(size_t)rowe[j] * O_DIM + cole[ni]] = acc[fr][ni][j] * os + bve[ni];
            }
        }
    }
}

// ---------------------------------------------------------------------------
extern "C" void kernel_launch(void* const* d_in, const int* in_sizes, int n_in,
                              void* d_out, int out_size, void* d_ws, size_t ws_size,
                              hipStream_t stream) {
    const float* x      = (const float*)d_in[0];
    const float* weight = (const float*)d_in[1];
    const float* bias   = (const float*)d_in[2];
    const float* gate_w = (const float*)d_in[3];
    const float* ics    = (const float*)d_in[4];
    const float* ocs    = (const float*)d_in[5];
    float* out = (float*)d_out;

    unsigned short* xs = (unsigned short*)d_ws;                      // [N][H] bf16
    unsigned short* bw = xs + (size_t)N_ROWS * H_DIM;                // [O][H] bf16
    float* rw = (float*)(bw + (size_t)O_DIM * H_DIM);                // [N][4]

    sign_kernel<<<(O_DIM * H_DIM) / (256 * 4), 256, 0, stream>>>(weight, bw);
    route_scale_kernel<<<N_ROWS, 256, 0, stream>>>(x, gate_w, ics, rw, xs);
    gemm_bin_kernel<<<(N_ROWS / 256) * (O_DIM / 256), 512, 0, stream>>>(xs, bw, rw, ocs, bias, out);
}